// Round 1
// baseline (3463.575 us; speedup 1.0000x reference)
//
#include <hip/hip_runtime.h>
#include <math.h>

// Problem constants (4, 19, 512, 512) fp32
#define BB 4
#define CC 19
#define HH 512
#define WW 512
#define NSLICE (BB * CC)        // 76
#define SLICE  (HH * WW)        // 262144
#define W4     (WW / 4)         // 128 float4 per row
#define EPS    1e-12f
#define NEGINF (-INFINITY)

// time-tiling params
#define TSTEPS 16
#define RROWS  64
#define AROWS  96               // RROWS + 2*TSTEPS
#define NPASS  16               // 256 / TSTEPS
#define RBLK   8                // HH / RROWS

// thread geometry: 1024 threads = 16 waves; wave = one 6-row strip spanning
// the full 512-col width (64 lanes x 8 cols). 96 floats persistent/thread
// -> <=128 total regs -> 4 waves/SIMD (2x the old 12-row/512-thr version).
#define NW   16                 // waves (strips) per block
#define ROWS 6                  // rows per thread
#define THREADS 1024

// ---------------------------------------------------------------------------
__global__ void init_kernel(const float* __restrict__ x, float* __restrict__ cur) {
    int t = blockIdx.x * blockDim.x + threadIdx.x;
    const float4* x4 = (const float4*)x;
    float4* c4 = (float4*)cur;
    float4 v = x4[t];
    int pix = t << 2;
    int s = pix & (SLICE - 1);
    int i = s >> 9;
    int j0 = s & 511;
    float4 o;
    o.x = -v.x; o.y = -v.y; o.z = -v.z; o.w = -v.w;
    if (i == 0 || i == HH - 1) {
        o.x = 1.0f; o.y = 1.0f; o.z = 1.0f; o.w = 1.0f;
    } else {
        if (j0 == 0)        o.x = 1.0f;
        if (j0 == WW - 4)   o.w = 1.0f;
    }
    c4[t] = o;
}

// ---------------------------------------------------------------------------
// one pass = TSTEPS fused (maxpool3x3 * x) steps on a 512x96 tile.
//
// vs previous version (158.7us/pass, 2 waves/SIMD, 2 barriers/step):
//  * 1024 threads, 6 rows/thread -> 96 persistent floats -> 4 waves/SIMD.
//  * double-buffered LDS halo snapshot -> ONE __syncthreads per step
//    (step t reads buf[t&1]; step t+2 rewrites it only after step t+1's
//    barrier, which happens-after all step-t reads drained).
//  * separable pool, VERTICAL FIRST: v[r]=max3(c[r-1],c[r],c[r+1]) reads the
//    persistent register array directly (no rolling F8 h-state, no hrow on
//    halo rows), then one horizontal max3 pass (2 shuffles/row), then *x.
//    ~3 VALU/px (v_max3 fusion) vs ~5.6 before.
//  * in-place update with a 1-row "pending" buffer: row r's result is
//    committed to c[r-1]'s slot one iteration late so row r+1 still sees
//    pre-step values.
// All loop trips/indices compile-time constant so cur/x stay in VGPRs.
__global__ __launch_bounds__(THREADS)
void pass_kernel(const float* __restrict__ in, const float* __restrict__ xg,
                 float* __restrict__ out) {
    const int tid  = threadIdx.x;
    const int lane = tid & 63;          // column group (8 cols each)
    const int w    = tid >> 6;          // wave = strip index 0..15
    const int bc   = blockIdx.x / RBLK;
    const int brow = blockIdx.x % RBLK;
    const int gstart = brow * RROWS - TSTEPS;       // tile row a=0 -> global row
    const int row0   = gstart + w * ROWS;           // this thread's r=0 global row
    const int col0   = lane * 8;
    const size_t sbase = (size_t)bc * SLICE;

    // double-buffered top/bottom row snapshots; [2 float4 per thread-row],
    // lane stride 16B -> conflict-free ds_read/write_b128. 128 KiB total.
    __shared__ float4 Tb[2][NW][2][64];
    __shared__ float4 Bb[2][NW][2][64];

    const float4 neg4 = make_float4(NEGINF, NEGINF, NEGINF, NEGINF);
    const float4 one4 = make_float4(1.f, 1.f, 1.f, 1.f);

    float4 cl[ROWS], cr[ROWS], xl[ROWS], xr_[ROWS];

#pragma unroll
    for (int r = 0; r < ROWS; ++r) {
        int grow = row0 + r;
        if (grow >= 0 && grow < HH) {               // wave-uniform branch
            const float4* p = (const float4*)(in + sbase + (size_t)grow * WW + col0);
            cl[r] = p[0]; cr[r] = p[1];
            const float4* q = (const float4*)(xg + sbase + (size_t)grow * WW + col0);
            xl[r] = q[0]; xr_[r] = q[1];
        } else {
            cl[r] = neg4; cr[r] = neg4; xl[r] = one4; xr_[r] = one4;
        }
    }

    for (int t = 0; t < TSTEPS; ++t) {
        const int buf = t & 1;
        // snapshot pre-step top/bottom rows for vertical neighbors
        Tb[buf][w][0][lane] = cl[0];
        Tb[buf][w][1][lane] = cr[0];
        Bb[buf][w][0][lane] = cl[ROWS - 1];
        Bb[buf][w][1][lane] = cr[ROWS - 1];
        __syncthreads();

        float4 upL, upR, dnL, dnR;
        if (w > 0) {                     // wave-uniform
            upL = Bb[buf][w - 1][0][lane];
            upR = Bb[buf][w - 1][1][lane];
        } else { upL = neg4; upR = neg4; }
        if (w < NW - 1) {
            dnL = Tb[buf][w + 1][0][lane];
            dnR = Tb[buf][w + 1][1][lane];
        } else { dnL = neg4; dnR = neg4; }

        float4 pendL, pendR;             // finished value of previous row
#pragma unroll
        for (int r = 0; r < ROWS; ++r) {
            // vertical 3-max straight from the (pre-step) register array
            float4 am1L = (r == 0)        ? upL : cl[r - 1];
            float4 am1R = (r == 0)        ? upR : cr[r - 1];
            float4 ap1L = (r == ROWS - 1) ? dnL : cl[r + 1];
            float4 ap1R = (r == ROWS - 1) ? dnR : cr[r + 1];
            float4 vl, vr;
            vl.x = fmaxf(fmaxf(am1L.x, cl[r].x), ap1L.x);
            vl.y = fmaxf(fmaxf(am1L.y, cl[r].y), ap1L.y);
            vl.z = fmaxf(fmaxf(am1L.z, cl[r].z), ap1L.z);
            vl.w = fmaxf(fmaxf(am1L.w, cl[r].w), ap1L.w);
            vr.x = fmaxf(fmaxf(am1R.x, cr[r].x), ap1R.x);
            vr.y = fmaxf(fmaxf(am1R.y, cr[r].y), ap1R.y);
            vr.z = fmaxf(fmaxf(am1R.z, cr[r].z), ap1R.z);
            vr.w = fmaxf(fmaxf(am1R.w, cr[r].w), ap1R.w);
            // horizontal 3-max: 2 in-wave shuffles per row
            float lpx = __shfl_up(vr.w, 1);
            float rpx = __shfl_down(vl.x, 1);
            if (lane == 0)  lpx = NEGINF;    // image left pad
            if (lane == 63) rpx = NEGINF;    // image right pad
            float4 hl, hr;
            hl.x = fmaxf(fmaxf(lpx,  vl.x), vl.y);
            hl.y = fmaxf(fmaxf(vl.x, vl.y), vl.z);
            hl.z = fmaxf(fmaxf(vl.y, vl.z), vl.w);
            hl.w = fmaxf(fmaxf(vl.z, vl.w), vr.x);
            hr.x = fmaxf(fmaxf(vl.w, vr.x), vr.y);
            hr.y = fmaxf(fmaxf(vr.x, vr.y), vr.z);
            hr.z = fmaxf(fmaxf(vr.y, vr.z), vr.w);
            hr.w = fmaxf(fmaxf(vr.z, vr.w), rpx);
            // multiply by x
            hl.x *= xl[r].x;  hl.y *= xl[r].y;  hl.z *= xl[r].z;  hl.w *= xl[r].w;
            hr.x *= xr_[r].x; hr.y *= xr_[r].y; hr.z *= xr_[r].z; hr.w *= xr_[r].w;
            // commit previous row (so row r+1 still reads pre-step c[r])
            if (r > 0) { cl[r - 1] = pendL; cr[r - 1] = pendR; }
            pendL = hl; pendR = hr;
        }
        cl[ROWS - 1] = pendL; cr[ROWS - 1] = pendR;

        // rows outside the image must be -inf before the next step's reads
#pragma unroll
        for (int r = 0; r < ROWS; ++r) {
            int grow = row0 + r;
            if (grow < 0 || grow >= HH) { cl[r] = neg4; cr[r] = neg4; }  // uniform
        }
        // no trailing barrier: next step writes the OTHER buffer; this
        // buffer is rewritten only after the next step's barrier.
    }

    // store valid center rows: tile rows a in [TSTEPS, TSTEPS+RROWS)
#pragma unroll
    for (int r = 0; r < ROWS; ++r) {
        int a = w * ROWS + r;            // wave-uniform condition
        if (a >= TSTEPS && a < TSTEPS + RROWS) {
            int grow = row0 + r;
            float4* p = (float4*)(out + sbase + (size_t)grow * WW + col0);
            p[0] = cl[r]; p[1] = cr[r];
        }
    }
}

// ---------------------------------------------------------------------------
// final: norm over channel dim (19), out = cur * x / max(||cur||_2, eps)
__global__ void norm_kernel(const float* __restrict__ cur,
                            const float* __restrict__ x,
                            float* __restrict__ out) {
    int t = blockIdx.x * blockDim.x + threadIdx.x;
    int j4 = t & (W4 - 1);
    int i  = (t >> 7) & (HH - 1);
    int b  = t >> 16;
    size_t off = (size_t)b * CC * SLICE + (size_t)i * WW + (j4 << 2);

    float4 vals[CC];
    float sx = 0.f, sy = 0.f, sz = 0.f, sw = 0.f;
#pragma unroll
    for (int c = 0; c < CC; ++c) {
        float4 v = *(const float4*)(cur + off + (size_t)c * SLICE);
        vals[c] = v;
        sx += v.x * v.x; sy += v.y * v.y; sz += v.z * v.z; sw += v.w * v.w;
    }
    float4 r;
    r.x = 1.0f / fmaxf(sqrtf(sx), EPS);
    r.y = 1.0f / fmaxf(sqrtf(sy), EPS);
    r.z = 1.0f / fmaxf(sqrtf(sz), EPS);
    r.w = 1.0f / fmaxf(sqrtf(sw), EPS);
#pragma unroll
    for (int c = 0; c < CC; ++c) {
        float4 xv = *(const float4*)(x + off + (size_t)c * SLICE);
        float4 o;
        o.x = vals[c].x * xv.x * r.x;
        o.y = vals[c].y * xv.y * r.y;
        o.z = vals[c].z * xv.z * r.z;
        o.w = vals[c].w * xv.w * r.w;
        *(float4*)(out + off + (size_t)c * SLICE) = o;
    }
}

// ---------------------------------------------------------------------------
extern "C" void kernel_launch(void* const* d_in, const int* in_sizes, int n_in,
                              void* d_out, int out_size, void* d_ws, size_t ws_size,
                              hipStream_t stream) {
    const float* x = (const float*)d_in[0];
    float* out = (float*)d_out;
    float* ws  = (float*)d_ws;        // >= 79,691,776 B

    const int initBlocks = NSLICE * SLICE / 4 / 256; // 19456
    const int passBlocks = NSLICE * RBLK;            // 608
    const int normBlocks = BB * HH * W4 / 256;       // 1024

    init_kernel<<<initBlocks, 256, 0, stream>>>(x, ws);
    float* a = ws;
    float* b = out;
    for (int it = 0; it < NPASS; ++it) {
        pass_kernel<<<passBlocks, THREADS, 0, stream>>>(a, x, b);
        float* tmp = a; a = b; b = tmp;
    }
    // NPASS even -> result back in ws
    norm_kernel<<<normBlocks, 256, 0, stream>>>(ws, x, out);
}

// Round 2
// 3441.333 us; speedup vs baseline: 1.0065x; 1.0065x over previous
//
#include <hip/hip_runtime.h>
#include <math.h>

// Problem constants (4, 19, 512, 512) fp32
#define BB 4
#define CC 19
#define HH 512
#define WW 512
#define NSLICE (BB * CC)        // 76
#define SLICE  (HH * WW)        // 262144
#define W4     (WW / 4)         // 128 float4 per row
#define EPS    1e-12f
#define NEGINF (-INFINITY)

// time-tiling params
#define TSTEPS 16
#define RROWS  64
#define AROWS  96               // RROWS + 2*TSTEPS
#define NPASS  16               // 256 / TSTEPS
#define RBLK   8                // HH / RROWS

// thread geometry: 1024 threads = 16 waves; wave = one 6-row strip spanning
// the full 512-col width (64 lanes x 8 cols). 96 floats persistent/thread.
// __launch_bounds__(1024, 4): min 4 waves/EU -> VGPR cap 128 (R1 failure:
// default cap 64 -> 96 persistent floats spilled to scratch, WRITE_SIZE
// 97->183 MB/pass, dur 158->221us. 128 KiB LDS already limits to 1 block/CU
// = 4 waves/SIMD, so capping below 128 buys nothing).
#define NW   16                 // waves (strips) per block
#define ROWS 6                  // rows per thread
#define THREADS 1024

// ---------------------------------------------------------------------------
__global__ void init_kernel(const float* __restrict__ x, float* __restrict__ cur) {
    int t = blockIdx.x * blockDim.x + threadIdx.x;
    const float4* x4 = (const float4*)x;
    float4* c4 = (float4*)cur;
    float4 v = x4[t];
    int pix = t << 2;
    int s = pix & (SLICE - 1);
    int i = s >> 9;
    int j0 = s & 511;
    float4 o;
    o.x = -v.x; o.y = -v.y; o.z = -v.z; o.w = -v.w;
    if (i == 0 || i == HH - 1) {
        o.x = 1.0f; o.y = 1.0f; o.z = 1.0f; o.w = 1.0f;
    } else {
        if (j0 == 0)        o.x = 1.0f;
        if (j0 == WW - 4)   o.w = 1.0f;
    }
    c4[t] = o;
}

// ---------------------------------------------------------------------------
// one pass = TSTEPS fused (maxpool3x3 * x) steps on a 512x96 tile.
//
//  * 1024 threads, 6 rows/thread -> 96 persistent floats; VGPR cap 128 via
//    __launch_bounds__(1024,4) -> 4 waves/SIMD, no spill.
//  * double-buffered LDS halo snapshot -> ONE __syncthreads per step
//    (step t reads buf[t&1]; buf is rewritten only at step t+2, which is
//    after step t+1's barrier, which happens-after all step-t reads).
//  * separable pool, VERTICAL FIRST: v[r]=max3(c[r-1],c[r],c[r+1]) reads the
//    persistent register array directly, then one horizontal max3 pass
//    (2 shuffles/row), then *x.
//  * halo rows are read from LDS LAZILY inside the r-loop (r==0 / r==ROWS-1
//    only, consumed immediately) instead of hoisted into registers -> -16
//    regs of step-body pressure vs R1.
//  * in-place update with a 1-row "pend" buffer: row r's result committed to
//    c[r-1]'s slot one iteration late so row r+1 still sees pre-step values.
// All loop trips/indices compile-time constant so cur/x stay in VGPRs.
__global__ __launch_bounds__(THREADS, 4)
void pass_kernel(const float* __restrict__ in, const float* __restrict__ xg,
                 float* __restrict__ out) {
    const int tid  = threadIdx.x;
    const int lane = tid & 63;          // column group (8 cols each)
    const int w    = tid >> 6;          // wave = strip index 0..15
    const int bc   = blockIdx.x / RBLK;
    const int brow = blockIdx.x % RBLK;
    const int gstart = brow * RROWS - TSTEPS;       // tile row a=0 -> global row
    const int row0   = gstart + w * ROWS;           // this thread's r=0 global row
    const int col0   = lane * 8;
    const size_t sbase = (size_t)bc * SLICE;

    // double-buffered top/bottom row snapshots; lane stride 16B ->
    // conflict-free ds_read/write_b128. 128 KiB total -> 1 block/CU.
    __shared__ float4 Tb[2][NW][2][64];
    __shared__ float4 Bb[2][NW][2][64];

    const float4 neg4 = make_float4(NEGINF, NEGINF, NEGINF, NEGINF);
    const float4 one4 = make_float4(1.f, 1.f, 1.f, 1.f);

    float4 cl[ROWS], cr[ROWS], xl[ROWS], xr_[ROWS];

#pragma unroll
    for (int r = 0; r < ROWS; ++r) {
        int grow = row0 + r;
        if (grow >= 0 && grow < HH) {               // wave-uniform branch
            const float4* p = (const float4*)(in + sbase + (size_t)grow * WW + col0);
            cl[r] = p[0]; cr[r] = p[1];
            const float4* q = (const float4*)(xg + sbase + (size_t)grow * WW + col0);
            xl[r] = q[0]; xr_[r] = q[1];
        } else {
            cl[r] = neg4; cr[r] = neg4; xl[r] = one4; xr_[r] = one4;
        }
    }

    for (int t = 0; t < TSTEPS; ++t) {
        const int buf = t & 1;
        // snapshot pre-step top/bottom rows for vertical neighbors
        Tb[buf][w][0][lane] = cl[0];
        Tb[buf][w][1][lane] = cr[0];
        Bb[buf][w][0][lane] = cl[ROWS - 1];
        Bb[buf][w][1][lane] = cr[ROWS - 1];
        __syncthreads();

        float4 pendL, pendR;             // finished value of previous row
#pragma unroll
        for (int r = 0; r < ROWS; ++r) {
            // neighbor rows (original, pre-step values)
            float4 am1L, am1R, ap1L, ap1R;
            if (r == 0) {
                if (w > 0) {             // wave-uniform
                    am1L = Bb[buf][w - 1][0][lane];
                    am1R = Bb[buf][w - 1][1][lane];
                } else { am1L = neg4; am1R = neg4; }
            } else { am1L = cl[r - 1]; am1R = cr[r - 1]; }
            if (r == ROWS - 1) {
                if (w < NW - 1) {        // wave-uniform
                    ap1L = Tb[buf][w + 1][0][lane];
                    ap1R = Tb[buf][w + 1][1][lane];
                } else { ap1L = neg4; ap1R = neg4; }
            } else { ap1L = cl[r + 1]; ap1R = cr[r + 1]; }

            // vertical 3-max
            float4 vl, vr;
            vl.x = fmaxf(fmaxf(am1L.x, cl[r].x), ap1L.x);
            vl.y = fmaxf(fmaxf(am1L.y, cl[r].y), ap1L.y);
            vl.z = fmaxf(fmaxf(am1L.z, cl[r].z), ap1L.z);
            vl.w = fmaxf(fmaxf(am1L.w, cl[r].w), ap1L.w);
            vr.x = fmaxf(fmaxf(am1R.x, cr[r].x), ap1R.x);
            vr.y = fmaxf(fmaxf(am1R.y, cr[r].y), ap1R.y);
            vr.z = fmaxf(fmaxf(am1R.z, cr[r].z), ap1R.z);
            vr.w = fmaxf(fmaxf(am1R.w, cr[r].w), ap1R.w);
            // horizontal 3-max: 2 in-wave shuffles per row
            float lpx = __shfl_up(vr.w, 1);
            float rpx = __shfl_down(vl.x, 1);
            if (lane == 0)  lpx = NEGINF;    // image left pad
            if (lane == 63) rpx = NEGINF;    // image right pad
            float4 hl, hr;
            hl.x = fmaxf(fmaxf(lpx,  vl.x), vl.y);
            hl.y = fmaxf(fmaxf(vl.x, vl.y), vl.z);
            hl.z = fmaxf(fmaxf(vl.y, vl.z), vl.w);
            hl.w = fmaxf(fmaxf(vl.z, vl.w), vr.x);
            hr.x = fmaxf(fmaxf(vl.w, vr.x), vr.y);
            hr.y = fmaxf(fmaxf(vr.x, vr.y), vr.z);
            hr.z = fmaxf(fmaxf(vr.y, vr.z), vr.w);
            hr.w = fmaxf(fmaxf(vr.z, vr.w), rpx);
            // multiply by x
            hl.x *= xl[r].x;  hl.y *= xl[r].y;  hl.z *= xl[r].z;  hl.w *= xl[r].w;
            hr.x *= xr_[r].x; hr.y *= xr_[r].y; hr.z *= xr_[r].z; hr.w *= xr_[r].w;
            // commit previous row (so row r+1 still reads pre-step c[r])
            if (r > 0) { cl[r - 1] = pendL; cr[r - 1] = pendR; }
            pendL = hl; pendR = hr;
        }
        cl[ROWS - 1] = pendL; cr[ROWS - 1] = pendR;

        // rows outside the image must be -inf before the next step's reads
#pragma unroll
        for (int r = 0; r < ROWS; ++r) {
            int grow = row0 + r;
            if (grow < 0 || grow >= HH) { cl[r] = neg4; cr[r] = neg4; }  // uniform
        }
        // no trailing barrier: next step writes the OTHER buffer; this
        // buffer is rewritten only after the next step's barrier.
    }

    // store valid center rows: tile rows a in [TSTEPS, TSTEPS+RROWS)
#pragma unroll
    for (int r = 0; r < ROWS; ++r) {
        int a = w * ROWS + r;            // wave-uniform condition
        if (a >= TSTEPS && a < TSTEPS + RROWS) {
            int grow = row0 + r;
            float4* p = (float4*)(out + sbase + (size_t)grow * WW + col0);
            p[0] = cl[r]; p[1] = cr[r];
        }
    }
}

// ---------------------------------------------------------------------------
// final: norm over channel dim (19), out = cur * x / max(||cur||_2, eps)
__global__ void norm_kernel(const float* __restrict__ cur,
                            const float* __restrict__ x,
                            float* __restrict__ out) {
    int t = blockIdx.x * blockDim.x + threadIdx.x;
    int j4 = t & (W4 - 1);
    int i  = (t >> 7) & (HH - 1);
    int b  = t >> 16;
    size_t off = (size_t)b * CC * SLICE + (size_t)i * WW + (j4 << 2);

    float4 vals[CC];
    float sx = 0.f, sy = 0.f, sz = 0.f, sw = 0.f;
#pragma unroll
    for (int c = 0; c < CC; ++c) {
        float4 v = *(const float4*)(cur + off + (size_t)c * SLICE);
        vals[c] = v;
        sx += v.x * v.x; sy += v.y * v.y; sz += v.z * v.z; sw += v.w * v.w;
    }
    float4 r;
    r.x = 1.0f / fmaxf(sqrtf(sx), EPS);
    r.y = 1.0f / fmaxf(sqrtf(sy), EPS);
    r.z = 1.0f / fmaxf(sqrtf(sz), EPS);
    r.w = 1.0f / fmaxf(sqrtf(sw), EPS);
#pragma unroll
    for (int c = 0; c < CC; ++c) {
        float4 xv = *(const float4*)(x + off + (size_t)c * SLICE);
        float4 o;
        o.x = vals[c].x * xv.x * r.x;
        o.y = vals[c].y * xv.y * r.y;
        o.z = vals[c].z * xv.z * r.z;
        o.w = vals[c].w * xv.w * r.w;
        *(float4*)(out + off + (size_t)c * SLICE) = o;
    }
}

// ---------------------------------------------------------------------------
extern "C" void kernel_launch(void* const* d_in, const int* in_sizes, int n_in,
                              void* d_out, int out_size, void* d_ws, size_t ws_size,
                              hipStream_t stream) {
    const float* x = (const float*)d_in[0];
    float* out = (float*)d_out;
    float* ws  = (float*)d_ws;        // >= 79,691,776 B

    const int initBlocks = NSLICE * SLICE / 4 / 256; // 19456
    const int passBlocks = NSLICE * RBLK;            // 608
    const int normBlocks = BB * HH * W4 / 256;       // 1024

    init_kernel<<<initBlocks, 256, 0, stream>>>(x, ws);
    float* a = ws;
    float* b = out;
    for (int it = 0; it < NPASS; ++it) {
        pass_kernel<<<passBlocks, THREADS, 0, stream>>>(a, x, b);
        float* tmp = a; a = b; b = tmp;
    }
    // NPASS even -> result back in ws
    norm_kernel<<<normBlocks, 256, 0, stream>>>(ws, x, out);
}